// Round 5
// baseline (867.358 us; speedup 1.0000x reference)
//
#include <hip/hip_runtime.h>
#include <hip/hip_cooperative_groups.h>

namespace cg = cooperative_groups;

// Problem constants
#define DIMC 192
#define HID  48          // DIM / RED
#define HW   65536       // 256*256
#define WIDTH 256
#define NPLANE 768       // B * DIM

// ---------------------------------------------------------------------------
// Fused cooperative kernel. Grid = 768 blocks x 256 threads = EXACTLY
// 3 blocks/CU on 256 CUs (LDS 49.2 KiB/block -> 3/CU; VGPR ~80 << 170).
// Block i owns rows [chunk*64, chunk*64+64) of plane c (c = i>>2, chunk=i&3)
// for every sample. Per sample:
//   phase A: stage the 64-row tile on-chip (wave w: rows w*16..w*16+3 in
//            REGISTERS (survive grid.sync), rows w*16+4..+15 in LDS slots
//            w*12..w*12+11) while accumulating the plane partial sum -> pp.
//   grid.sync()
//   phase B: weight-gen (t = relu(BN(pooled@w1^T)); 4 unmasked taps from w2),
//            then conv entirely from registers/LDS, write-only to HBM.
// x is read ONCE (pure-read phase ~6.1 TB/s), out written once (pure-write
// phase ~6.6 TB/s) — the two regimes measured at ceiling. The ~4.1 TB/s
// mixed-stream re-read is gone.
// ---------------------------------------------------------------------------
__global__ __launch_bounds__(256, 3) void k_fused(
    const float* __restrict__ x,
    float* __restrict__ pp,             // [768*4] chunk sums
    const float* __restrict__ w1,       // [48,192]
    const float* __restrict__ gamma,
    const float* __restrict__ beta,
    const float* __restrict__ rmean,
    const float* __restrict__ rvar,
    const float* __restrict__ w2,       // [1728,48]
    const float* __restrict__ b2,       // [1728]
    const float* __restrict__ bias,
    float* __restrict__ out)
{
    const int c     = blockIdx.x >> 2;  // 0..191 channel
    const int chunk = blockIdx.x & 3;   // 0..3, 64 rows each
    const int r0    = chunk << 6;
    const int tid   = threadIdx.x;
    const int wave  = tid >> 6;
    const int lane  = tid & 63;

    __shared__ float4 XT[48 * 64];      // 12 rows/wave, slot (wave*12+j) = row wave*16+4+j
    __shared__ float P[DIMC];
    __shared__ float T[HID];
    __shared__ float W4v[4];
    __shared__ float wsum[4];

    float4 R[4];                        // rows wave*16 .. wave*16+3 (persist across sync)

    for (int b = 0; b < 4; ++b) {
        const int plane = b * DIMC + c;
        const float4* xp4 = (const float4*)(x + (size_t)plane * HW);

        // ---- phase A: stage + pool ----
        float s = 0.f;
#pragma unroll
        for (int j = 0; j < 4; ++j) {
            R[j] = xp4[(r0 + wave * 16 + j) * 64 + lane];
            s += (R[j].x + R[j].y) + (R[j].z + R[j].w);
        }
#pragma unroll
        for (int j = 0; j < 12; ++j) {
            float4 v = xp4[(r0 + wave * 16 + 4 + j) * 64 + lane];
            XT[(wave * 12 + j) * 64 + lane] = v;
            s += (v.x + v.y) + (v.z + v.w);
        }
#pragma unroll
        for (int off = 32; off > 0; off >>= 1) s += __shfl_down(s, off, 64);
        if (lane == 0) wsum[wave] = s;
        __syncthreads();
        if (tid == 0) {
            pp[plane * 4 + chunk] = (wsum[0] + wsum[1]) + (wsum[2] + wsum[3]);
            __threadfence();            // device-scope visibility before grid barrier
        }
        cg::this_grid().sync();

        // ---- phase B: weight generation ----
        if (tid < DIMC) {
            float4 v = ((const float4*)pp)[b * DIMC + tid];   // 4 chunk sums
            P[tid] = ((v.x + v.y) + (v.z + v.w)) * (1.0f / 65536.0f);
        }
        __syncthreads();
        {
            const int g = tid >> 2, l = tid & 3;   // 48 groups of 4 lanes
            if (g < HID) {
                const float* wr = w1 + g * DIMC;
                float acc = 0.f;
#pragma unroll 8
                for (int d = l; d < DIMC; d += 4) acc += P[d] * wr[d];
                acc += __shfl_xor(acc, 1, 64);
                acc += __shfl_xor(acc, 2, 64);
                if (l == 0) {
                    const float inv = rsqrtf(rvar[g] + 1e-5f);
                    float v = gamma[g] * (acc - rmean[g]) * inv + beta[g];
                    T[g] = v > 0.f ? v : 0.f;
                }
            }
            __syncthreads();
            if (tid < 4) {                          // 4 unmasked taps of channel c
                const int o = c * 9 + tid;
                const float* wr = w2 + o * HID;
                float acc = b2[o];
#pragma unroll
                for (int j = 0; j < HID; ++j) acc += T[j] * wr[j];
                W4v[tid] = acc;
            }
            __syncthreads();
        }
        const float4 wt = make_float4(W4v[0], W4v[1], W4v[2], W4v[3]); // {w00,w01,w02,w10}
        const float bs = bias[c];

        // ---- conv: 16 rows per wave, all inputs on-chip ----
        float4* op = (float4*)(out + (size_t)plane * HW);
        float4 a;                                   // row y-1
        {
            const int gy = r0 + wave * 16 - 1;
            if (gy < 0)          a = make_float4(0.f, 0.f, 0.f, 0.f);
            else if (wave == 0)  a = xp4[gy * 64 + lane];           // halo row (L2-hot)
            else                 a = XT[(wave * 12 - 1) * 64 + lane]; // row (w-1)*16+15
        }
#pragma unroll
        for (int rr = 0; rr < 16; ++rr) {
            float4 bb = (rr < 4) ? R[rr] : XT[(wave * 12 + (rr - 4)) * 64 + lane];
            float leftA  = __shfl_up(a.w, 1, 64);   if (lane == 0)  leftA  = 0.f;
            float rightA = __shfl_down(a.x, 1, 64); if (lane == 63) rightA = 0.f;
            float leftB  = __shfl_up(bb.w, 1, 64);  if (lane == 0)  leftB  = 0.f;
            float4 o;
            o.x = wt.x * leftA + wt.y * a.x + wt.z * a.y    + wt.w * leftB + bs;
            o.y = wt.x * a.x   + wt.y * a.y + wt.z * a.z    + wt.w * bb.x  + bs;
            o.z = wt.x * a.y   + wt.y * a.z + wt.z * a.w    + wt.w * bb.y  + bs;
            o.w = wt.x * a.z   + wt.y * a.w + wt.z * rightA + wt.w * bb.z  + bs;
            op[(r0 + wave * 16 + rr) * 64 + lane] = o;
            a = bb;
        }
        __syncthreads();   // waves cross-read XT slot w*12-1; protect before restage
    }
}

// ---------------------------------------------------------------------------
// Fallback path (R2-proven structure) in case cooperative launch is refused.
// ---------------------------------------------------------------------------
__global__ __launch_bounds__(256) void k_pool_fb(const float* __restrict__ x,
                                                 float* __restrict__ pp) {
    const int plane = blockIdx.x >> 2;
    const int strip = blockIdx.x & 3;
    const float4* p = (const float4*)(x + (size_t)plane * HW + strip * 64 * WIDTH);
    const int t = threadIdx.x;
    float s = 0.f;
#pragma unroll
    for (int k = 0; k < 16; ++k) {
        float4 v = p[k * 256 + t];
        s += (v.x + v.y) + (v.z + v.w);
    }
#pragma unroll
    for (int off = 32; off > 0; off >>= 1) s += __shfl_down(s, off, 64);
    __shared__ float wsum[4];
    const int wave = t >> 6, lane = t & 63;
    if (lane == 0) wsum[wave] = s;
    __syncthreads();
    if (t == 0) pp[blockIdx.x] = (wsum[0] + wsum[1]) + (wsum[2] + wsum[3]);
}

__global__ __launch_bounds__(256) void k_conv_fb(
    const float* __restrict__ x, const float* __restrict__ pp,
    const float* __restrict__ w1, const float* __restrict__ gamma,
    const float* __restrict__ beta, const float* __restrict__ rmean,
    const float* __restrict__ rvar, const float* __restrict__ w2,
    const float* __restrict__ b2, const float* __restrict__ bias,
    float* __restrict__ out)
{
    const int plane = blockIdx.x >> 3;
    const int b = plane / DIMC;
    const int c = plane - b * DIMC;
    const int tid = threadIdx.x;
    __shared__ float P[DIMC];
    __shared__ float T[HID];
    __shared__ float W4v[4];
    if (tid < DIMC) {
        float4 v = ((const float4*)pp)[b * DIMC + tid];
        P[tid] = ((v.x + v.y) + (v.z + v.w)) * (1.0f / 65536.0f);
    }
    __syncthreads();
    {
        const int g = tid >> 2, l = tid & 3;
        if (g < HID) {
            const float* wr = w1 + g * DIMC;
            float acc = 0.f;
#pragma unroll 8
            for (int d = l; d < DIMC; d += 4) acc += P[d] * wr[d];
            acc += __shfl_xor(acc, 1, 64);
            acc += __shfl_xor(acc, 2, 64);
            if (l == 0) {
                const float inv = rsqrtf(rvar[g] + 1e-5f);
                float v = gamma[g] * (acc - rmean[g]) * inv + beta[g];
                T[g] = v > 0.f ? v : 0.f;
            }
        }
        __syncthreads();
        if (tid < 4) {
            const int o = c * 9 + tid;
            const float* wr = w2 + o * HID;
            float acc = b2[o];
#pragma unroll
            for (int j = 0; j < HID; ++j) acc += T[j] * wr[j];
            W4v[tid] = acc;
        }
        __syncthreads();
    }
    const float4 wt = make_float4(W4v[0], W4v[1], W4v[2], W4v[3]);
    const float bs = bias[c];
    const int wave = tid >> 6, lane = tid & 63;
    const int y0 = ((blockIdx.x & 7) << 5) + (wave << 3);
    const float4* xp = (const float4*)(x + (size_t)plane * HW);
    float4* op = (float4*)(out + (size_t)plane * HW);
    float4 a;
    if (y0 == 0) a = make_float4(0.f, 0.f, 0.f, 0.f);
    else         a = xp[(y0 - 1) * 64 + lane];
#pragma unroll
    for (int r = 0; r < 8; ++r) {
        const int y = y0 + r;
        float4 bb = xp[y * 64 + lane];
        float leftA  = __shfl_up(a.w, 1, 64);   if (lane == 0)  leftA  = 0.f;
        float rightA = __shfl_down(a.x, 1, 64); if (lane == 63) rightA = 0.f;
        float leftB  = __shfl_up(bb.w, 1, 64);  if (lane == 0)  leftB  = 0.f;
        float4 o;
        o.x = wt.x * leftA + wt.y * a.x + wt.z * a.y    + wt.w * leftB + bs;
        o.y = wt.x * a.x   + wt.y * a.y + wt.z * a.z    + wt.w * bb.x  + bs;
        o.z = wt.x * a.y   + wt.y * a.z + wt.z * a.w    + wt.w * bb.y  + bs;
        o.w = wt.x * a.z   + wt.y * a.w + wt.z * rightA + wt.w * bb.z  + bs;
        op[y * 64 + lane] = o;
        a = bb;
    }
}

// ---------------------------------------------------------------------------
extern "C" void kernel_launch(void* const* d_in, const int* in_sizes, int n_in,
                              void* d_out, int out_size, void* d_ws, size_t ws_size,
                              hipStream_t stream) {
    const float* x     = (const float*)d_in[0];
    const float* w1    = (const float*)d_in[1];
    const float* gamma = (const float*)d_in[2];
    const float* beta  = (const float*)d_in[3];
    const float* rmean = (const float*)d_in[4];
    const float* rvar  = (const float*)d_in[5];
    const float* w2    = (const float*)d_in[6];
    const float* b2    = (const float*)d_in[7];
    const float* bias  = (const float*)d_in[8];
    float* out = (float*)d_out;

    float* pp = (float*)d_ws;   // 768*4 chunk partial sums

    void* args[] = {(void*)&x, (void*)&pp, (void*)&w1, (void*)&gamma,
                    (void*)&beta, (void*)&rmean, (void*)&rvar, (void*)&w2,
                    (void*)&b2, (void*)&bias, (void*)&out};
    hipError_t err = hipLaunchCooperativeKernel((const void*)k_fused,
                                                dim3(NPLANE), dim3(256),
                                                args, 0, stream);
    if (err != hipSuccess) {
        // Fallback: proven 2-kernel path.
        k_pool_fb<<<NPLANE * 4, 256, 0, stream>>>(x, pp);
        k_conv_fb<<<NPLANE * 8, 256, 0, stream>>>(x, pp, w1, gamma, beta,
                                                  rmean, rvar, w2, b2, bias, out);
    }
}